// Round 1
// baseline (440.503 us; speedup 1.0000x reference)
//
#include <hip/hip_runtime.h>

// CREStereo grouped correlation with deformable 1D search window.
// B=2, C=256, H=96, W=192, GROUPS=4 (64 ch/group), K=9 candidates (x offs -4..4).
// One thread per output pixel-group (b,g,h,w); loops 64 channels x 9 candidates.
// Bilinear weights+indices computed once per thread per k; validity folded into
// weights (clamped index + zero weight == reference's masked gather).

namespace {
constexpr int kB = 2;
constexpr int kC = 256;
constexpr int kH = 96;
constexpr int kW = 192;
constexpr int kG = 4;
constexpr int kGC = kC / kG;   // 64
constexpr int kK = 9;
constexpr int kHW = kH * kW;
}

__global__ __launch_bounds__(256) void crestereo_corr_kernel(
    const float* __restrict__ left, const float* __restrict__ right,
    const float* __restrict__ flow, const float* __restrict__ extra,
    float* __restrict__ out)
{
  int t = blockIdx.x * blockDim.x + threadIdx.x;
  if (t >= kB * kG * kH * kW) return;
  int w = t % kW;
  int h = (t / kW) % kH;
  int g = (t / (kW * kH)) % kG;
  int b = t / (kW * kH * kG);

  int pix = h * kW + w;
  const float* flowb = flow + b * 2 * kHW + pix;
  float cx = (float)w + flowb[0];
  float cy = (float)h + flowb[kHW];

  const float* extb = extra + b * 2 * kK * kHW + pix;

  float wt[kK][4];
  int   idx[kK];
  int   dx[kK];
  int   dyw[kK];

  #pragma unroll
  for (int k = 0; k < kK; ++k) {
    float x = cx + (float)(k - 4) + extb[(2 * k + 0) * kHW];
    float y = cy + extb[(2 * k + 1) * kHW];
    float xf = floorf(x);
    float yf = floorf(y);
    float fx = x - xf, fy = y - yf;
    int ix0 = (int)xf, iy0 = (int)yf;
    int ix1 = ix0 + 1, iy1 = iy0 + 1;
    bool vx0 = (ix0 >= 0) && (ix0 < kW);
    bool vx1 = (ix1 >= 0) && (ix1 < kW);
    bool vy0 = (iy0 >= 0) && (iy0 < kH);
    bool vy1 = (iy1 >= 0) && (iy1 < kH);
    int xc0 = min(max(ix0, 0), kW - 1);
    int xc1 = min(max(ix1, 0), kW - 1);
    int yc0 = min(max(iy0, 0), kH - 1);
    int yc1 = min(max(iy1, 0), kH - 1);
    float wx0 = 1.f - fx, wy0 = 1.f - fy;
    wt[k][0] = wx0 * wy0 * ((vx0 && vy0) ? 1.f : 0.f);
    wt[k][1] = fx  * wy0 * ((vx1 && vy0) ? 1.f : 0.f);
    wt[k][2] = wx0 * fy  * ((vx0 && vy1) ? 1.f : 0.f);
    wt[k][3] = fx  * fy  * ((vx1 && vy1) ? 1.f : 0.f);
    idx[k] = yc0 * kW + xc0;
    dx[k]  = xc1 - xc0;          // 0 or 1 (0 when clamped at an edge)
    dyw[k] = (yc1 - yc0) * kW;   // 0 or W
  }

  const float* Rb = right + (size_t)(b * kC + g * kGC) * kHW;
  const float* Lb = left  + (size_t)(b * kC + g * kGC) * kHW + pix;

  float acc[kK];
  #pragma unroll
  for (int k = 0; k < kK; ++k) acc[k] = 0.f;

  for (int c = 0; c < kGC; ++c) {
    float l = Lb[(size_t)c * kHW];
    const float* Rc = Rb + (size_t)c * kHW;
    #pragma unroll
    for (int k = 0; k < kK; ++k) {
      float v00 = Rc[idx[k]];
      float v01 = Rc[idx[k] + dx[k]];
      float v10 = Rc[idx[k] + dyw[k]];
      float v11 = Rc[idx[k] + dx[k] + dyw[k]];
      acc[k] += l * (wt[k][0] * v00 + wt[k][1] * v01 +
                     wt[k][2] * v10 + wt[k][3] * v11);
    }
  }

  float* outb = out + ((size_t)(b * kG + g) * kK) * kHW + pix;
  #pragma unroll
  for (int k = 0; k < kK; ++k)
    outb[(size_t)k * kHW] = acc[k] * (1.f / kGC);
}

extern "C" void kernel_launch(void* const* d_in, const int* in_sizes, int n_in,
                              void* d_out, int out_size, void* d_ws, size_t ws_size,
                              hipStream_t stream) {
  const float* left  = (const float*)d_in[0];
  const float* right = (const float*)d_in[1];
  const float* flow  = (const float*)d_in[2];
  const float* extra = (const float*)d_in[3];
  float* out = (float*)d_out;

  int total = kB * kG * kH * kW;       // 147456 threads
  int block = 256;
  int grid = (total + block - 1) / block;  // 576 blocks
  crestereo_corr_kernel<<<grid, block, 0, stream>>>(left, right, flow, extra, out);
}

// Round 2
// 363.597 us; speedup vs baseline: 1.2115x; 1.2115x over previous
//
#include <hip/hip_runtime.h>

// CREStereo grouped correlation, round 2: k moved into the grid.
// One thread per (b, g, k, h, w) -> 1.33M threads / 5184 blocks (vs 576 before).
// Each thread computes one candidate's bilinear weights once, then loops the
// 64 channels of its group: 1 coalesced left load + 4 spatially-clustered
// gathers per channel, unrolled x4 for memory-level parallelism.
// Round-1 counters showed latency-bound (VALUBusy 4.6%, HBM 5.7%, occ 16.6%).

namespace {
constexpr int kB = 2;
constexpr int kC = 256;
constexpr int kH = 96;
constexpr int kW = 192;
constexpr int kG = 4;
constexpr int kGC = kC / kG;   // 64
constexpr int kK = 9;
constexpr int kHW = kH * kW;
}

__global__ __launch_bounds__(256) void crestereo_corr_kernel(
    const float* __restrict__ left, const float* __restrict__ right,
    const float* __restrict__ flow, const float* __restrict__ extra,
    float* __restrict__ out)
{
  int t = blockIdx.x * blockDim.x + threadIdx.x;
  // layout: (((b*G + g)*K + k)*H + h)*W + w   -- w innermost for coalescing,
  // k just above (h,w) so adjacent blocks share right-feature planes in L2.
  int w = t % kW;
  int h = (t / kW) % kH;
  int k = (t / kHW) % kK;
  int g = (t / (kHW * kK)) % kG;
  int b = t / (kHW * kK * kG);

  int pix = h * kW + w;
  const float* flowb = flow + b * 2 * kHW + pix;
  float x = (float)(w + (k - 4)) + flowb[0];
  float y = (float)h + flowb[kHW];

  const float* extb = extra + (size_t)(b * 2 * kK + 2 * k) * kHW + pix;
  x += extb[0];
  y += extb[kHW];

  float xf = floorf(x);
  float yf = floorf(y);
  float fx = x - xf, fy = y - yf;
  int ix0 = (int)xf, iy0 = (int)yf;
  int ix1 = ix0 + 1, iy1 = iy0 + 1;
  bool vx0 = (ix0 >= 0) && (ix0 < kW);
  bool vx1 = (ix1 >= 0) && (ix1 < kW);
  bool vy0 = (iy0 >= 0) && (iy0 < kH);
  bool vy1 = (iy1 >= 0) && (iy1 < kH);
  int xc0 = min(max(ix0, 0), kW - 1);
  int xc1 = min(max(ix1, 0), kW - 1);
  int yc0 = min(max(iy0, 0), kH - 1);
  int yc1 = min(max(iy1, 0), kH - 1);
  float wx0 = 1.f - fx, wy0 = 1.f - fy;
  float w00 = wx0 * wy0 * ((vx0 && vy0) ? 1.f : 0.f);
  float w01 = fx  * wy0 * ((vx1 && vy0) ? 1.f : 0.f);
  float w10 = wx0 * fy  * ((vx0 && vy1) ? 1.f : 0.f);
  float w11 = fx  * fy  * ((vx1 && vy1) ? 1.f : 0.f);
  int idx = yc0 * kW + xc0;
  int dx  = xc1 - xc0;           // 0 or 1
  int dyw = (yc1 - yc0) * kW;    // 0 or W

  const float* Rb = right + (size_t)(b * kC + g * kGC) * kHW + idx;
  const float* Lb = left  + (size_t)(b * kC + g * kGC) * kHW + pix;

  float acc = 0.f;
  #pragma unroll 4
  for (int c = 0; c < kGC; ++c) {
    const float* Rc = Rb + (size_t)c * kHW;
    float l   = Lb[(size_t)c * kHW];
    float v00 = Rc[0];
    float v01 = Rc[dx];
    float v10 = Rc[dyw];
    float v11 = Rc[dx + dyw];
    acc += l * (w00 * v00 + w01 * v01 + w10 * v10 + w11 * v11);
  }

  out[(size_t)(((b * kG + g) * kK + k)) * kHW + pix] = acc * (1.f / kGC);
}

extern "C" void kernel_launch(void* const* d_in, const int* in_sizes, int n_in,
                              void* d_out, int out_size, void* d_ws, size_t ws_size,
                              hipStream_t stream) {
  const float* left  = (const float*)d_in[0];
  const float* right = (const float*)d_in[1];
  const float* flow  = (const float*)d_in[2];
  const float* extra = (const float*)d_in[3];
  float* out = (float*)d_out;

  int total = kB * kG * kK * kH * kW;      // 1,327,104 threads
  int block = 256;
  int grid = (total + block - 1) / block;  // 5184 blocks
  crestereo_corr_kernel<<<grid, block, 0, stream>>>(left, right, flow, extra, out);
}

// Round 3
// 214.823 us; speedup vs baseline: 2.0505x; 1.6925x over previous
//
#include <hip/hip_runtime.h>

// CREStereo grouped correlation, round 3: channels-last layout.
// Pre-pass transposes left/right [b,c,h,w] -> [b,h,w,c] into d_ws.
// Main kernel: one wave per (b,pixel); lane i owns channels 4i..4i+3 (float4).
// Every bilinear tap is a wave-uniform address -> ONE dwordx4 load covers all
// 256 channels (vs 256+ scalar gathers in round 2). Group sums via 16-lane
// shfl_xor butterfly. Round-2 counters: VALUBusy 11.8%, HBM 18%, occ 66% ->
// VMEM-instruction/latency bound; this cuts load instructions ~78x.

namespace {
constexpr int kB = 2;
constexpr int kC = 256;
constexpr int kH = 96;
constexpr int kW = 192;
constexpr int kG = 4;
constexpr int kGC = kC / kG;              // 64
constexpr int kK = 9;
constexpr int kHW = kH * kW;              // 18432
constexpr size_t kPlane = (size_t)kC * kHW;  // elems per batch per tensor
}

// ---- transpose [C][HW] -> [HW][C], per (b, tensor) tile 64x64 ----
__global__ __launch_bounds__(256) void transpose_kernel(
    const float* __restrict__ left, const float* __restrict__ right,
    float* __restrict__ left_t, float* __restrict__ right_t)
{
  __shared__ float tile[64][65];
  int pt = blockIdx.x;          // pixel tile 0..287
  int ct = blockIdx.y;          // channel tile 0..3
  int z  = blockIdx.z;          // b*2 + tensor
  int b  = z >> 1;
  const float* in  = (z & 1) ? right   : left;
  float*       dst = (z & 1) ? right_t : left_t;
  int x = threadIdx.x & 63;
  int y = threadIdx.x >> 6;     // 0..3
  int p0 = pt * 64, c0 = ct * 64;
  const float* inb = in  + (size_t)b * kPlane;
  float*      outb = dst + (size_t)b * kPlane;
  #pragma unroll
  for (int i = 0; i < 16; ++i) {
    int c = y * 16 + i;
    tile[c][x] = inb[(size_t)(c0 + c) * kHW + p0 + x];
  }
  __syncthreads();
  #pragma unroll
  for (int i = 0; i < 16; ++i) {
    int p = y * 16 + i;
    outb[(size_t)(p0 + p) * kC + c0 + x] = tile[x][p];
  }
}

// ---- main: one wave per (b,pixel), lane = 4 channels ----
__global__ __launch_bounds__(256) void corr_cl_kernel(
    const float* __restrict__ left_t, const float* __restrict__ right_t,
    const float* __restrict__ flow, const float* __restrict__ extra,
    float* __restrict__ out)
{
  int wave = blockIdx.x * 4 + (threadIdx.x >> 6);  // 0 .. B*HW-1
  int lane = threadIdx.x & 63;
  int pix = wave % kHW;
  int b   = wave / kHW;
  int w = pix % kW, h = pix / kW;

  const float4 l4 = ((const float4*)(left_t + ((size_t)b * kHW + pix) * kC))[lane];

  const float* flowb = flow + (size_t)b * 2 * kHW + pix;
  float bx = (float)w + flowb[0];
  float by = (float)h + flowb[kHW];
  const float* extb = extra + (size_t)b * 2 * kK * kHW + pix;

  const float* Rb = right_t + (size_t)b * kPlane;

  float res[kK];
  #pragma unroll
  for (int k = 0; k < kK; ++k) {
    float xx = bx + (float)(k - 4) + extb[(size_t)(2 * k) * kHW];
    float yy = by + extb[(size_t)(2 * k + 1) * kHW];
    float xf = floorf(xx), yf = floorf(yy);
    float fx = xx - xf, fy = yy - yf;
    int ix0 = (int)xf, iy0 = (int)yf;
    int ix1 = ix0 + 1, iy1 = iy0 + 1;
    bool vx0 = (ix0 >= 0) && (ix0 < kW);
    bool vx1 = (ix1 >= 0) && (ix1 < kW);
    bool vy0 = (iy0 >= 0) && (iy0 < kH);
    bool vy1 = (iy1 >= 0) && (iy1 < kH);
    int xc0 = min(max(ix0, 0), kW - 1);
    int xc1 = min(max(ix1, 0), kW - 1);
    int yc0 = min(max(iy0, 0), kH - 1);
    int yc1 = min(max(iy1, 0), kH - 1);
    float wx0 = 1.f - fx, wy0 = 1.f - fy;
    float w00 = wx0 * wy0 * ((vx0 && vy0) ? 1.f : 0.f);
    float w01 = fx  * wy0 * ((vx1 && vy0) ? 1.f : 0.f);
    float w10 = wx0 * fy  * ((vx0 && vy1) ? 1.f : 0.f);
    float w11 = fx  * fy  * ((vx1 && vy1) ? 1.f : 0.f);

    const float4* t00p = (const float4*)(Rb + (size_t)(yc0 * kW + xc0) * kC);
    const float4* t01p = (const float4*)(Rb + (size_t)(yc0 * kW + xc1) * kC);
    const float4* t10p = (const float4*)(Rb + (size_t)(yc1 * kW + xc0) * kC);
    const float4* t11p = (const float4*)(Rb + (size_t)(yc1 * kW + xc1) * kC);
    float4 t00 = t00p[lane];
    float4 t01 = t01p[lane];
    float4 t10 = t10p[lane];
    float4 t11 = t11p[lane];

    float sx = w00 * t00.x + w01 * t01.x + w10 * t10.x + w11 * t11.x;
    float sy = w00 * t00.y + w01 * t01.y + w10 * t10.y + w11 * t11.y;
    float sz = w00 * t00.z + w01 * t01.z + w10 * t10.z + w11 * t11.z;
    float sw = w00 * t00.w + w01 * t01.w + w10 * t10.w + w11 * t11.w;
    res[k] = l4.x * sx + l4.y * sy + l4.z * sz + l4.w * sw;
  }

  int g = lane >> 4;
  #pragma unroll
  for (int k = 0; k < kK; ++k) {
    float r = res[k];
    r += __shfl_xor(r, 1);
    r += __shfl_xor(r, 2);
    r += __shfl_xor(r, 4);
    r += __shfl_xor(r, 8);
    if ((lane & 15) == 0)
      out[((size_t)(b * kG + g) * kK + k) * kHW + pix] = r * (1.f / kGC);
  }
}

// ---- fallback (round-2 kernel) if workspace too small ----
__global__ __launch_bounds__(256) void crestereo_corr_fallback(
    const float* __restrict__ left, const float* __restrict__ right,
    const float* __restrict__ flow, const float* __restrict__ extra,
    float* __restrict__ out)
{
  int t = blockIdx.x * blockDim.x + threadIdx.x;
  int w = t % kW;
  int h = (t / kW) % kH;
  int k = (t / kHW) % kK;
  int g = (t / (kHW * kK)) % kG;
  int b = t / (kHW * kK * kG);

  int pix = h * kW + w;
  const float* flowb = flow + b * 2 * kHW + pix;
  float x = (float)(w + (k - 4)) + flowb[0];
  float y = (float)h + flowb[kHW];
  const float* extb = extra + (size_t)(b * 2 * kK + 2 * k) * kHW + pix;
  x += extb[0];
  y += extb[kHW];

  float xf = floorf(x), yf = floorf(y);
  float fx = x - xf, fy = y - yf;
  int ix0 = (int)xf, iy0 = (int)yf;
  int ix1 = ix0 + 1, iy1 = iy0 + 1;
  bool vx0 = (ix0 >= 0) && (ix0 < kW);
  bool vx1 = (ix1 >= 0) && (ix1 < kW);
  bool vy0 = (iy0 >= 0) && (iy0 < kH);
  bool vy1 = (iy1 >= 0) && (iy1 < kH);
  int xc0 = min(max(ix0, 0), kW - 1);
  int xc1 = min(max(ix1, 0), kW - 1);
  int yc0 = min(max(iy0, 0), kH - 1);
  int yc1 = min(max(iy1, 0), kH - 1);
  float wx0 = 1.f - fx, wy0 = 1.f - fy;
  float w00 = wx0 * wy0 * ((vx0 && vy0) ? 1.f : 0.f);
  float w01 = fx  * wy0 * ((vx1 && vy0) ? 1.f : 0.f);
  float w10 = wx0 * fy  * ((vx0 && vy1) ? 1.f : 0.f);
  float w11 = fx  * fy  * ((vx1 && vy1) ? 1.f : 0.f);
  int idx = yc0 * kW + xc0;
  int dx  = xc1 - xc0;
  int dyw = (yc1 - yc0) * kW;

  const float* Rb = right + (size_t)(b * kC + g * kGC) * kHW + idx;
  const float* Lb = left  + (size_t)(b * kC + g * kGC) * kHW + pix;

  float acc = 0.f;
  #pragma unroll 4
  for (int c = 0; c < kGC; ++c) {
    const float* Rc = Rb + (size_t)c * kHW;
    float l   = Lb[(size_t)c * kHW];
    acc += l * (w00 * Rc[0] + w01 * Rc[dx] + w10 * Rc[dyw] + w11 * Rc[dx + dyw]);
  }
  out[(size_t)((b * kG + g) * kK + k) * kHW + pix] = acc * (1.f / kGC);
}

extern "C" void kernel_launch(void* const* d_in, const int* in_sizes, int n_in,
                              void* d_out, int out_size, void* d_ws, size_t ws_size,
                              hipStream_t stream) {
  const float* left  = (const float*)d_in[0];
  const float* right = (const float*)d_in[1];
  const float* flow  = (const float*)d_in[2];
  const float* extra = (const float*)d_in[3];
  float* out = (float*)d_out;

  size_t need = 2 * (size_t)kB * kPlane * sizeof(float);  // ~75.5 MB
  if (ws_size >= need) {
    float* left_t  = (float*)d_ws;
    float* right_t = left_t + (size_t)kB * kPlane;
    dim3 tgrid(kHW / 64, kC / 64, kB * 2);   // 288 x 4 x 4
    transpose_kernel<<<tgrid, 256, 0, stream>>>(left, right, left_t, right_t);
    int waves = kB * kHW;                    // 36864 waves, 1 pixel each
    corr_cl_kernel<<<waves / 4, 256, 0, stream>>>(left_t, right_t, flow, extra, out);
  } else {
    int total = kB * kG * kK * kH * kW;
    crestereo_corr_fallback<<<(total + 255) / 256, 256, 0, stream>>>(
        left, right, flow, extra, out);
  }
}